// Round 15
// baseline (2979.399 us; speedup 1.0000x reference)
//
#include <hip/hip_runtime.h>

typedef unsigned short u16;
typedef unsigned int   u32;
typedef unsigned long long ull;
typedef __attribute__((ext_vector_type(8))) __bf16 bf16x8;
typedef __attribute__((ext_vector_type(4))) float  f32x4;

#define DEV static __device__ __forceinline__

DEV u16 f2bf(float f) {
    u32 u = __float_as_uint(f);
    u = (u + 0x7fffu + ((u >> 16) & 1u)) >> 16;
    return (u16)u;
}
DEV float bf2f(u16 b) { return __uint_as_float(((u32)b) << 16); }
DEV bf16x8 ldfrag(const u16* p) { return *reinterpret_cast<const bf16x8*>(p); }

// ------------------------------- cvt f32->bf16 (+ zero hbuf: replaces k_init2)
__global__ __launch_bounds__(256) void k_cvt(const float* __restrict__ in, u16* __restrict__ out, int n,
                                             ull* __restrict__ hbuf) {
    int i = (blockIdx.x * 256 + threadIdx.x) * 4;
    if (i < n) {
        float4 v = *reinterpret_cast<const float4*>(in + i);
        ushort4 o; o.x = f2bf(v.x); o.y = f2bf(v.y); o.z = f2bf(v.z); o.w = f2bf(v.w);
        *reinterpret_cast<ushort4*>(out + i) = o;
    }
    if (blockIdx.x < 32)
        hbuf[blockIdx.x * 256 + threadIdx.x] = 0ull;   // tags must reset every launch
}

// ---------------- fused transpose of the four 512x512 weights (z selects src)
__global__ __launch_bounds__(256) void k_tr4(const float* __restrict__ Wq, const float* __restrict__ Wk,
                                             const float* __restrict__ Wv, const float* __restrict__ Wo,
                                             u16* __restrict__ WqkvT, u16* __restrict__ WoT) {
    __shared__ float t[32][33];
    int zz = blockIdx.z;
    const float* in = (zz == 0) ? Wq : (zz == 1) ? Wk : (zz == 2) ? Wv : Wo;
    u16* out = (zz < 3) ? (WqkvT + (size_t)zz * 512 * 512) : WoT;
    int c0 = blockIdx.x * 32, r0 = blockIdx.y * 32;
    int tx = threadIdx.x % 32, ty = threadIdx.x / 32;
    for (int i = 0; i < 32; i += 8)
        t[ty + i][tx] = in[(r0 + ty + i) * 512 + c0 + tx];
    __syncthreads();
    for (int i = 0; i < 32; i += 8)
        out[(size_t)(c0 + ty + i) * 512 + r0 + tx] = f2bf(t[tx][ty + i]);
}

// ---------------- fused transpose of lstm kernels (512x2048, z: 0=lk 1=lr)
__global__ __launch_bounds__(256) void k_tr2(const float* __restrict__ lk, const float* __restrict__ lr,
                                             u16* __restrict__ kT, u16* __restrict__ rT) {
    __shared__ float t[32][33];
    const float* in = blockIdx.z ? lr : lk;
    u16* out = blockIdx.z ? rT : kT;
    int c0 = blockIdx.x * 32, r0 = blockIdx.y * 32;
    int tx = threadIdx.x % 32, ty = threadIdx.x / 32;
    for (int i = 0; i < 32; i += 8)
        t[ty + i][tx] = in[(r0 + ty + i) * 2048 + c0 + tx];
    __syncthreads();
    for (int i = 0; i < 32; i += 8)
        out[(size_t)(c0 + ty + i) * 512 + r0 + tx] = f2bf(t[tx][ty + i]);
}

// ---------------- transpose V (cols 1024..1535 of QKV) -> Vt[b][h][s] (bf16)
__global__ __launch_bounds__(256) void k_tr_v(const u16* __restrict__ qkv, u16* __restrict__ vt) {
    __shared__ u16 t[32][33];
    int b = blockIdx.z;
    int s0 = blockIdx.x * 32, h0 = blockIdx.y * 32;
    int tx = threadIdx.x % 32, ty = threadIdx.x / 32;
    for (int i = 0; i < 32; i += 8)
        t[ty + i][tx] = qkv[(size_t)(b * 1024 + s0 + ty + i) * 1536 + 1024 + h0 + tx];
    __syncthreads();
    for (int i = 0; i < 32; i += 8)
        vt[(size_t)b * 512 * 1024 + (size_t)(h0 + ty + i) * 1024 + s0 + tx] = t[tx][ty + i];
}

// ---------------- bf16 GEMM: C[M,N] = A[M,K] * Bt[N,K]^T (+bias), bf16 out
// LDS-staged via global_load_lds width=16, linear LDS dest + pre-swizzled
// global source (slot ^= (row>>1)&3), same XOR on ds_read (involution).
__global__ __launch_bounds__(256) void k_gemm(const u16* __restrict__ A, const u16* __restrict__ Bt,
                                              u16* __restrict__ Cb, const float* __restrict__ bias,
                                              int M, int N, int K, int ldc, int xp_mode) {
    int mtiles = M >> 7;
    int mt = blockIdx.x % mtiles, nt = blockIdx.x / mtiles;
    int m0 = mt << 7, n0 = nt << 7;
    int lane = threadIdx.x & 63, wid = threadIdx.x >> 6;
    int wm = (wid >> 1) * 64, wn = (wid & 1) * 64;
    int ls = lane & 15, g = lane >> 4;
    __shared__ u16 As[128 * 32], Bs[128 * 32];
    f32x4 acc[4][4] = {};

    int srow[2], soff[2];
    #pragma unroll
    for (int t = 0; t < 2; t++) {
        int r16 = t * 4 + wid;
        srow[t] = r16 * 16 + (lane >> 2);
        soff[t] = ((lane & 3) ^ ((srow[t] >> 1) & 3)) * 8;
    }

    for (int k0 = 0; k0 < K; k0 += 32) {
        #pragma unroll
        for (int t = 0; t < 2; t++) {
            int r16 = t * 4 + wid;
            __builtin_amdgcn_global_load_lds(
                (const __attribute__((address_space(1))) void*)(A + (size_t)(m0 + srow[t]) * K + k0 + soff[t]),
                (__attribute__((address_space(3))) void*)(As + r16 * 512), 16, 0, 0);
            __builtin_amdgcn_global_load_lds(
                (const __attribute__((address_space(1))) void*)(Bt + (size_t)(n0 + srow[t]) * K + k0 + soff[t]),
                (__attribute__((address_space(3))) void*)(Bs + r16 * 512), 16, 0, 0);
        }
        asm volatile("s_waitcnt vmcnt(0)" ::: "memory");
        __syncthreads();
        bf16x8 a[4], b[4];
        #pragma unroll
        for (int i = 0; i < 4; i++) {
            int row = wm + i * 16 + ls;
            a[i] = ldfrag(&As[row * 32 + (g ^ ((row >> 1) & 3)) * 8]);
        }
        #pragma unroll
        for (int j = 0; j < 4; j++) {
            int row = wn + j * 16 + ls;
            b[j] = ldfrag(&Bs[row * 32 + (g ^ ((row >> 1) & 3)) * 8]);
        }
        #pragma unroll
        for (int i = 0; i < 4; i++)
            #pragma unroll
            for (int j = 0; j < 4; j++)
                acc[i][j] = __builtin_amdgcn_mfma_f32_16x16x32_bf16(a[i], b[j], acc[i][j], 0, 0, 0);
        __syncthreads();
    }
    #pragma unroll
    for (int i = 0; i < 4; i++)
        #pragma unroll
        for (int j = 0; j < 4; j++) {
            int col = n0 + wn + j * 16 + ls;
            float bv = bias ? bias[col] : 0.f;
            #pragma unroll
            for (int r = 0; r < 4; r++) {
                int row = m0 + wm + i * 16 + g * 4 + r;
                u16 val = f2bf(acc[i][j][r] + bv);
                if (xp_mode) {
                    int b_ = row >> 10, s_ = row & 1023;
                    int gate = col >> 9, u = col & 511;
                    int jj = u >> 5, uu = u & 31;
                    Cb[(((size_t)jj * 1024 + s_) * 16 + b_) * 128 + gate * 32 + uu] = val;
                } else {
                    Cb[(size_t)row * ldc + col] = val;
                }
            }
        }
}

// ---------------- fused attention: per (batch, 32-row q tile)  [QBLK=32, R14-proven]
__global__ __launch_bounds__(256) void k_attn(const u16* __restrict__ qkv, const u16* __restrict__ vt,
                                              u16* __restrict__ attnO) {
    __shared__ u16 P[32 * 1024];     // 64 KB
    __shared__ float mbuf[4][32], lbuf[4][32];
    int b = blockIdx.x >> 5, qt = blockIdx.x & 31;
    int q0 = qt * 32;
    int lane = threadIdx.x & 63, w = threadIdx.x >> 6;
    int ls = lane & 15, g = lane >> 4;
    const float sc = 0.04419417382f;  // 1/sqrt(512)

    f32x4 acc[2][16] = {};
    const u16* Qp0 = qkv + (size_t)(b * 1024 + q0 + ls) * 1536 + g * 8;
    const u16* Qp1 = Qp0 + (size_t)16 * 1536;
    const u16* Kp = qkv + (size_t)(b * 1024 + w * 256 + ls) * 1536 + 512 + g * 8;
    for (int k0 = 0; k0 < 512; k0 += 32) {
        bf16x8 a0 = ldfrag(Qp0 + k0);
        bf16x8 a1 = ldfrag(Qp1 + k0);
        #pragma unroll
        for (int f = 0; f < 16; f++) {
            bf16x8 bb = ldfrag(Kp + (size_t)f * 16 * 1536 + k0);
            acc[0][f] = __builtin_amdgcn_mfma_f32_16x16x32_bf16(a0, bb, acc[0][f], 0, 0, 0);
            acc[1][f] = __builtin_amdgcn_mfma_f32_16x16x32_bf16(a1, bb, acc[1][f], 0, 0, 0);
        }
    }
    float mx[2][4] = {{-1e30f, -1e30f, -1e30f, -1e30f}, {-1e30f, -1e30f, -1e30f, -1e30f}};
    #pragma unroll
    for (int t = 0; t < 2; t++)
        #pragma unroll
        for (int f = 0; f < 16; f++)
            #pragma unroll
            for (int r = 0; r < 4; r++) mx[t][r] = fmaxf(mx[t][r], acc[t][f][r]);
    #pragma unroll
    for (int d = 1; d < 16; d <<= 1)
        #pragma unroll
        for (int t = 0; t < 2; t++)
            #pragma unroll
            for (int r = 0; r < 4; r++) mx[t][r] = fmaxf(mx[t][r], __shfl_xor(mx[t][r], d, 64));
    if (ls == 0)
        #pragma unroll
        for (int t = 0; t < 2; t++)
            #pragma unroll
            for (int r = 0; r < 4; r++) mbuf[w][t * 16 + g * 4 + r] = mx[t][r];
    __syncthreads();
    float m[2][4];
    #pragma unroll
    for (int t = 0; t < 2; t++)
        #pragma unroll
        for (int r = 0; r < 4; r++) {
            int row = t * 16 + g * 4 + r;
            m[t][r] = fmaxf(fmaxf(mbuf[0][row], mbuf[1][row]), fmaxf(mbuf[2][row], mbuf[3][row])) * sc;
        }
    float sum[2][4] = {};
    #pragma unroll
    for (int t = 0; t < 2; t++)
        #pragma unroll
        for (int f = 0; f < 16; f++)
            #pragma unroll
            for (int r = 0; r < 4; r++) {
                int row = t * 16 + g * 4 + r, col = w * 256 + f * 16 + ls;
                float e = __expf(acc[t][f][r] * sc - m[t][r]);
                sum[t][r] += e;
                P[(row * 1024 + col) ^ ((row & 7) << 3)] = f2bf(e);
            }
    #pragma unroll
    for (int d = 1; d < 16; d <<= 1)
        #pragma unroll
        for (int t = 0; t < 2; t++)
            #pragma unroll
            for (int r = 0; r < 4; r++) sum[t][r] += __shfl_xor(sum[t][r], d, 64);
    if (ls == 0)
        #pragma unroll
        for (int t = 0; t < 2; t++)
            #pragma unroll
            for (int r = 0; r < 4; r++) lbuf[w][t * 16 + g * 4 + r] = sum[t][r];
    __syncthreads();

    f32x4 o[2][8] = {};
    const bf16x8* Pv = reinterpret_cast<const bf16x8*>(P);
    const u16* Vp = vt + (size_t)b * 512 * 1024 + (size_t)(w * 128 + ls) * 1024 + g * 8;
    for (int k0 = 0; k0 < 1024; k0 += 32) {
        bf16x8 a0 = Pv[(ls * 128 + (k0 >> 3) + g) ^ (ls & 7)];
        bf16x8 a1 = Pv[((16 + ls) * 128 + (k0 >> 3) + g) ^ (ls & 7)];
        #pragma unroll
        for (int q = 0; q < 8; q++) {
            bf16x8 bb = ldfrag(Vp + (size_t)q * 16 * 1024 + k0);
            o[0][q] = __builtin_amdgcn_mfma_f32_16x16x32_bf16(a0, bb, o[0][q], 0, 0, 0);
            o[1][q] = __builtin_amdgcn_mfma_f32_16x16x32_bf16(a1, bb, o[1][q], 0, 0, 0);
        }
    }
    #pragma unroll
    for (int t = 0; t < 2; t++)
        #pragma unroll
        for (int q = 0; q < 8; q++) {
            int col = w * 128 + q * 16 + ls;
            #pragma unroll
            for (int r = 0; r < 4; r++) {
                int row = t * 16 + g * 4 + r;
                float l = lbuf[0][row] + lbuf[1][row] + lbuf[2][row] + lbuf[3][row];
                attnO[(size_t)(b * 1024 + q0 + row) * 512 + col] = f2bf(o[t][q][r] / l);
            }
        }
}

// ---------------- proj Wo + residual(emb) + LayerNorm -> out1 (f32 + bf16)
__global__ __launch_bounds__(256) void k_projln(const u16* __restrict__ attnO, const u16* __restrict__ WoT,
                                                const float* __restrict__ emb, const float* __restrict__ gamma,
                                                const float* __restrict__ beta, float* __restrict__ out1f,
                                                u16* __restrict__ out1b) {
    __shared__ float buf[16][512];
    int m0 = blockIdx.x * 16;
    int lane = threadIdx.x & 63, w = threadIdx.x >> 6;
    int ls = lane & 15, g = lane >> 4;
    f32x4 acc[8] = {};
    const u16* Ap = attnO + (size_t)(m0 + ls) * 512 + g * 8;
    const u16* Bp = WoT + (size_t)(w * 128 + ls) * 512 + g * 8;
    for (int k0 = 0; k0 < 512; k0 += 32) {
        bf16x8 a = ldfrag(Ap + k0);
        #pragma unroll
        for (int q = 0; q < 8; q++) {
            bf16x8 bb = ldfrag(Bp + (size_t)q * 16 * 512 + k0);
            acc[q] = __builtin_amdgcn_mfma_f32_16x16x32_bf16(a, bb, acc[q], 0, 0, 0);
        }
    }
    #pragma unroll
    for (int q = 0; q < 8; q++) {
        int col = w * 128 + q * 16 + ls;
        #pragma unroll
        for (int r = 0; r < 4; r++) {
            int row = g * 4 + r;
            buf[row][col] = acc[q][r] + emb[(size_t)(m0 + row) * 512 + col];
        }
    }
    __syncthreads();
    int row = threadIdx.x >> 4, c0 = threadIdx.x & 15;
    float s = 0.f, s2 = 0.f;
    for (int c = c0; c < 512; c += 16) { float x = buf[row][c]; s += x; s2 += x * x; }
    #pragma unroll
    for (int d = 1; d < 16; d <<= 1) { s += __shfl_xor(s, d, 64); s2 += __shfl_xor(s2, d, 64); }
    float mu = s * (1.f / 512.f);
    float var = s2 * (1.f / 512.f) - mu * mu;
    float rs = rsqrtf(var + 1e-3f);
    for (int c = c0; c < 512; c += 16) {
        float y = gamma[c] * (buf[row][c] - mu) * rs + beta[c];
        out1f[(size_t)(m0 + row) * 512 + c] = y;
        out1b[(size_t)(m0 + row) * 512 + c] = f2bf(y);
    }
}

// ---------------- persistent LSTM scan: 16 blocks, all 1024 steps in-kernel.
// Tagged-u64 exchange + pre-sample sleep (R15: sleep 16, testing saturation).
__global__ __launch_bounds__(256) void k_lstm(const u16* __restrict__ xpp, const u16* __restrict__ rT,
                                              ull* hbuf /*2 slots x 4096 u64*/, float* __restrict__ hseq) {
    int j = blockIdx.x;
    int tid = threadIdx.x;
    int lane = tid & 63, w = tid >> 6;
    int ls = lane & 15, g = lane >> 4;
    __shared__ float z[16][132];   // padded row stride
    __shared__ u16 hb[8192];       // h[16][512], XOR-swizzled: byte ^= (row&7)<<4
    __shared__ u16 xb[2][2048];
    u32* hb32 = (u32*)hb;

    // R slice -> registers
    bf16x8 rf[2][16];
    {
        const u16* Bp = rT + (size_t)(w * 512 + j * 32 + ls) * 512 + g * 8;
        #pragma unroll
        for (int q = 0; q < 2; q++)
            #pragma unroll
            for (int kk = 0; kk < 16; kk++)
                rf[q][kk] = ldfrag(Bp + (size_t)q * 16 * 512 + kk * 32);
    }
    float cA = 0.f, cB = 0.f;

    for (int i = tid; i < 4096; i += 256) hb32[i] = 0;
    {
        uint4 v = *reinterpret_cast<const uint4*>(xpp + ((size_t)j * 1024) * 2048 + tid * 8);
        *reinterpret_cast<uint4*>(&xb[0][tid * 8]) = v;
    }
    __syncthreads();

    int bb_ = tid >> 4, uu0 = (tid & 15) * 2;
    int eprod = bb_ * 256 + j * 16 + (uu0 >> 1);

    for (int s = 0; s < 1024; s++) {
        uint4 nx;
        if (s + 1 < 1024)
            nx = *reinterpret_cast<const uint4*>(xpp + ((size_t)j * 1024 + s + 1) * 2048 + tid * 8);

        // z = h @ R
        f32x4 acc[2] = {};
        #pragma unroll
        for (int kk = 0; kk < 16; kk++) {
            int aidx = (ls * 512 + kk * 32 + g * 8) ^ ((ls & 7) << 3);
            bf16x8 a = ldfrag(&hb[aidx]);
            acc[0] = __builtin_amdgcn_mfma_f32_16x16x32_bf16(a, rf[0][kk], acc[0], 0, 0, 0);
            acc[1] = __builtin_amdgcn_mfma_f32_16x16x32_bf16(a, rf[1][kk], acc[1], 0, 0, 0);
        }
        #pragma unroll
        for (int q = 0; q < 2; q++)
            #pragma unroll
            for (int r = 0; r < 4; r++)
                z[g * 4 + r][w * 32 + q * 16 + ls] = acc[q][r];
        __syncthreads();   // (A) all hb reads + z writes complete

        // gates
        float hres0, hres1;
        {
            const u16* xr = &xb[s & 1][bb_ * 128];
            #pragma unroll
            for (int p = 0; p < 2; p++) {
                int uu = uu0 + p;
                float zi = z[bb_][uu]      + bf2f(xr[uu]);
                float zf = z[bb_][32 + uu] + bf2f(xr[32 + uu]);
                float zg = z[bb_][64 + uu] + bf2f(xr[64 + uu]);
                float zo = z[bb_][96 + uu] + bf2f(xr[96 + uu]);
                float ii = 1.f / (1.f + __expf(-zi));
                float ff = 1.f / (1.f + __expf(-zf));
                float gg = fmaxf(zg, 0.f);
                float oo = 1.f / (1.f + __expf(-zo));
                float cp = p ? cB : cA;
                float cn = ff * cp + ii * gg;
                if (p) cB = cn; else cA = cn;
                float h = oo * fmaxf(cn, 0.f);
                if (p) hres1 = h; else hres0 = h;
            }
        }

        if (s + 1 < 1024) {
            // publish h(s+1): single tagged u64, fire-and-forget
            ull pk = ((ull)((u32)f2bf(hres0) | ((u32)f2bf(hres1) << 16)) << 32) | (u32)(s + 1);
            __hip_atomic_store(hbuf + ((s + 1) & 1) * 4096 + eprod, pk,
                               __ATOMIC_RELAXED, __HIP_MEMORY_SCOPE_AGENT);
        }
        // hseq out (HBM, overlaps the exchange)
        *reinterpret_cast<float2*>(&hseq[((size_t)bb_ * 1024 + s) * 512 + j * 32 + uu0]) =
            make_float2(hres0, hres1);
        if (s + 1 < 1024)
            *reinterpret_cast<uint4*>(&xb[(s + 1) & 1][tid * 8]) = nx;

        if (s + 1 < 1024) {
            // delay first sample so producer stores are LLC-visible
            __builtin_amdgcn_s_sleep(16);   // R15: test 16 vs R13's 14
            const ull* src = hbuf + ((s + 1) & 1) * 4096;
            u32 want = (u32)(s + 1);
            ull v[16];
            #pragma unroll
            for (int i = 0; i < 16; i++)
                v[i] = __hip_atomic_load(src + i * 256 + tid,
                                         __ATOMIC_RELAXED, __HIP_MEMORY_SCOPE_AGENT);
            u32 stale = 0;
            #pragma unroll
            for (int i = 0; i < 16; i++)
                stale |= (u32)((u32)v[i] != want) << i;
            while (stale) {
                __builtin_amdgcn_s_sleep(1);
                #pragma unroll
                for (int i = 0; i < 16; i++)
                    if (stale & (1u << i))
                        v[i] = __hip_atomic_load(src + i * 256 + tid,
                                                 __ATOMIC_RELAXED, __HIP_MEMORY_SCOPE_AGENT);
                u32 ns = 0;
                #pragma unroll
                for (int i = 0; i < 16; i++)
                    ns |= (u32)((u32)v[i] != want) << i;
                stale = ns;
            }
            // refill hb (own targets only; barrier (A) fenced all prior reads)
            #pragma unroll
            for (int i = 0; i < 16; i++) {
                int e = i * 256 + tid;
                int b = e >> 8, up = e & 255;
                hb32[(b * 256 + up) ^ ((b & 7) << 2)] = (u32)(v[i] >> 32);
            }
            __syncthreads();   // (C) refill visible before next MFMA
        }
    }
}

// ---------------- final LN in place on d_out: out = LN(d_out + out1f)
__global__ __launch_bounds__(256) void k_finln(float* __restrict__ io, const float* __restrict__ res,
                                               const float* __restrict__ gamma, const float* __restrict__ beta) {
    int m0 = blockIdx.x * 16;
    int row = threadIdx.x >> 4, c0 = threadIdx.x & 15;
    size_t base = (size_t)(m0 + row) * 512;
    float x[32];
    float s = 0.f, s2 = 0.f;
    #pragma unroll
    for (int i = 0; i < 32; i++) {
        int cc = c0 + i * 16;
        x[i] = io[base + cc] + res[base + cc];
        s += x[i]; s2 += x[i] * x[i];
    }
    #pragma unroll
    for (int d = 1; d < 16; d <<= 1) { s += __shfl_xor(s, d, 64); s2 += __shfl_xor(s2, d, 64); }
    float mu = s * (1.f / 512.f);
    float var = s2 * (1.f / 512.f) - mu * mu;
    float rs = rsqrtf(var + 1e-3f);
    #pragma unroll
    for (int i = 0; i < 32; i++) {
        int cc = c0 + i * 16;
        io[base + cc] = gamma[cc] * (x[i] - mu) * rs + beta[cc];
    }
}

extern "C" void kernel_launch(void* const* d_in, const int* in_sizes, int n_in,
                              void* d_out, int out_size, void* d_ws, size_t ws_size,
                              hipStream_t stream) {
    (void)in_sizes; (void)n_in; (void)out_size; (void)ws_size;
    const float* emb   = (const float*)d_in[0];
    const float* Wq    = (const float*)d_in[1];
    const float* Wk    = (const float*)d_in[2];
    const float* Wv    = (const float*)d_in[3];
    const float* Wo    = (const float*)d_in[4];
    const float* gamma = (const float*)d_in[5];
    const float* beta  = (const float*)d_in[6];
    const float* lk    = (const float*)d_in[7];
    const float* lr    = (const float*)d_in[8];
    const float* lb    = (const float*)d_in[9];

    char* w = (char*)d_ws;
    size_t o = 0;
    u16* WqkvT = (u16*)(w + o); o += (size_t)1536 * 512 * 2;
    u16* WoT   = (u16*)(w + o); o += (size_t)512 * 512 * 2;
    u16* kT    = (u16*)(w + o); o += (size_t)2048 * 512 * 2;
    u16* rT    = (u16*)(w + o); o += (size_t)2048 * 512 * 2;
    u16* Xbf   = (u16*)(w + o); o += (size_t)16384 * 512 * 2;     // reused as attnO
    u16* QKV   = (u16*)(w + o); o += (size_t)16384 * 1536 * 2;    // reused (with Vt) as xpp
    u16* Vt    = (u16*)(w + o); o += (size_t)16 * 512 * 1024 * 2;
    float* out1f = (float*)(w + o); o += (size_t)16384 * 512 * 4;
    u16* out1b = (u16*)(w + o); o += (size_t)16384 * 512 * 2;
    ull* hbuf  = (ull*)(w + o);  o += (size_t)2 * 4096 * 8;
    u16* attnO = Xbf;   // Xbf dead after QKV GEMM
    u16* xpp   = QKV;   // QKV+Vt dead after attention
    float* outp = (float*)d_out;

    k_cvt<<<8192, 256, 0, stream>>>(emb, Xbf, 16384 * 512, hbuf);
    k_tr4<<<dim3(16, 16, 4), 256, 0, stream>>>(Wq, Wk, Wv, Wo, WqkvT, WoT);
    k_tr2<<<dim3(64, 16, 2), 256, 0, stream>>>(lk, lr, kT, rT);
    k_gemm<<<128 * 12, 256, 0, stream>>>(Xbf, WqkvT, QKV, nullptr, 16384, 1536, 512, 1536, 0);
    k_tr_v<<<dim3(32, 16, 16), 256, 0, stream>>>(QKV, Vt);
    k_attn<<<512, 256, 0, stream>>>(QKV, Vt, attnO);
    k_projln<<<1024, 256, 0, stream>>>(attnO, WoT, emb, gamma, beta, out1f, out1b);
    k_gemm<<<128 * 16, 256, 0, stream>>>(out1b, kT, xpp, lb, 16384, 2048, 512, 2048, 1);
    k_lstm<<<16, 256, 0, stream>>>(xpp, rT, hbuf, outp);
    k_finln<<<1024, 256, 0, stream>>>(outp, out1f, gamma, beta);
}

// Round 16
// 2972.611 us; speedup vs baseline: 1.0023x; 1.0023x over previous
//
#include <hip/hip_runtime.h>

typedef unsigned short u16;
typedef unsigned int   u32;
typedef unsigned long long ull;
typedef __attribute__((ext_vector_type(8))) __bf16 bf16x8;
typedef __attribute__((ext_vector_type(4))) float  f32x4;

#define DEV static __device__ __forceinline__

DEV u16 f2bf(float f) {
    u32 u = __float_as_uint(f);
    u = (u + 0x7fffu + ((u >> 16) & 1u)) >> 16;
    return (u16)u;
}
DEV float bf2f(u16 b) { return __uint_as_float(((u32)b) << 16); }
DEV bf16x8 ldfrag(const u16* p) { return *reinterpret_cast<const bf16x8*>(p); }

// ------------------------------- cvt f32->bf16 (+ zero hbuf: replaces k_init2)
__global__ __launch_bounds__(256) void k_cvt(const float* __restrict__ in, u16* __restrict__ out, int n,
                                             ull* __restrict__ hbuf) {
    int i = (blockIdx.x * 256 + threadIdx.x) * 4;
    if (i < n) {
        float4 v = *reinterpret_cast<const float4*>(in + i);
        ushort4 o; o.x = f2bf(v.x); o.y = f2bf(v.y); o.z = f2bf(v.z); o.w = f2bf(v.w);
        *reinterpret_cast<ushort4*>(out + i) = o;
    }
    if (blockIdx.x < 32)
        hbuf[blockIdx.x * 256 + threadIdx.x] = 0ull;   // tags must reset every launch
}

// ---------------- fused transpose of the four 512x512 weights (z selects src)
__global__ __launch_bounds__(256) void k_tr4(const float* __restrict__ Wq, const float* __restrict__ Wk,
                                             const float* __restrict__ Wv, const float* __restrict__ Wo,
                                             u16* __restrict__ WqkvT, u16* __restrict__ WoT) {
    __shared__ float t[32][33];
    int zz = blockIdx.z;
    const float* in = (zz == 0) ? Wq : (zz == 1) ? Wk : (zz == 2) ? Wv : Wo;
    u16* out = (zz < 3) ? (WqkvT + (size_t)zz * 512 * 512) : WoT;
    int c0 = blockIdx.x * 32, r0 = blockIdx.y * 32;
    int tx = threadIdx.x % 32, ty = threadIdx.x / 32;
    for (int i = 0; i < 32; i += 8)
        t[ty + i][tx] = in[(r0 + ty + i) * 512 + c0 + tx];
    __syncthreads();
    for (int i = 0; i < 32; i += 8)
        out[(size_t)(c0 + ty + i) * 512 + r0 + tx] = f2bf(t[tx][ty + i]);
}

// ---------------- fused transpose of lstm kernels (512x2048, z: 0=lk 1=lr)
__global__ __launch_bounds__(256) void k_tr2(const float* __restrict__ lk, const float* __restrict__ lr,
                                             u16* __restrict__ kT, u16* __restrict__ rT) {
    __shared__ float t[32][33];
    const float* in = blockIdx.z ? lr : lk;
    u16* out = blockIdx.z ? rT : kT;
    int c0 = blockIdx.x * 32, r0 = blockIdx.y * 32;
    int tx = threadIdx.x % 32, ty = threadIdx.x / 32;
    for (int i = 0; i < 32; i += 8)
        t[ty + i][tx] = in[(r0 + ty + i) * 2048 + c0 + tx];
    __syncthreads();
    for (int i = 0; i < 32; i += 8)
        out[(size_t)(c0 + ty + i) * 512 + r0 + tx] = f2bf(t[tx][ty + i]);
}

// ---------------- transpose V (cols 1024..1535 of QKV) -> Vt[b][h][s] (bf16)
__global__ __launch_bounds__(256) void k_tr_v(const u16* __restrict__ qkv, u16* __restrict__ vt) {
    __shared__ u16 t[32][33];
    int b = blockIdx.z;
    int s0 = blockIdx.x * 32, h0 = blockIdx.y * 32;
    int tx = threadIdx.x % 32, ty = threadIdx.x / 32;
    for (int i = 0; i < 32; i += 8)
        t[ty + i][tx] = qkv[(size_t)(b * 1024 + s0 + ty + i) * 1536 + 1024 + h0 + tx];
    __syncthreads();
    for (int i = 0; i < 32; i += 8)
        vt[(size_t)b * 512 * 1024 + (size_t)(h0 + ty + i) * 1024 + s0 + tx] = t[tx][ty + i];
}

// ---------------- bf16 GEMM: C[M,N] = A[M,K] * Bt[N,K]^T (+bias), bf16 out
// LDS-staged via global_load_lds width=16, linear LDS dest + pre-swizzled
// global source (slot ^= (row>>1)&3), same XOR on ds_read (involution).
__global__ __launch_bounds__(256) void k_gemm(const u16* __restrict__ A, const u16* __restrict__ Bt,
                                              u16* __restrict__ Cb, const float* __restrict__ bias,
                                              int M, int N, int K, int ldc, int xp_mode) {
    int mtiles = M >> 7;
    int mt = blockIdx.x % mtiles, nt = blockIdx.x / mtiles;
    int m0 = mt << 7, n0 = nt << 7;
    int lane = threadIdx.x & 63, wid = threadIdx.x >> 6;
    int wm = (wid >> 1) * 64, wn = (wid & 1) * 64;
    int ls = lane & 15, g = lane >> 4;
    __shared__ u16 As[128 * 32], Bs[128 * 32];
    f32x4 acc[4][4] = {};

    int srow[2], soff[2];
    #pragma unroll
    for (int t = 0; t < 2; t++) {
        int r16 = t * 4 + wid;
        srow[t] = r16 * 16 + (lane >> 2);
        soff[t] = ((lane & 3) ^ ((srow[t] >> 1) & 3)) * 8;
    }

    for (int k0 = 0; k0 < K; k0 += 32) {
        #pragma unroll
        for (int t = 0; t < 2; t++) {
            int r16 = t * 4 + wid;
            __builtin_amdgcn_global_load_lds(
                (const __attribute__((address_space(1))) void*)(A + (size_t)(m0 + srow[t]) * K + k0 + soff[t]),
                (__attribute__((address_space(3))) void*)(As + r16 * 512), 16, 0, 0);
            __builtin_amdgcn_global_load_lds(
                (const __attribute__((address_space(1))) void*)(Bt + (size_t)(n0 + srow[t]) * K + k0 + soff[t]),
                (__attribute__((address_space(3))) void*)(Bs + r16 * 512), 16, 0, 0);
        }
        asm volatile("s_waitcnt vmcnt(0)" ::: "memory");
        __syncthreads();
        bf16x8 a[4], b[4];
        #pragma unroll
        for (int i = 0; i < 4; i++) {
            int row = wm + i * 16 + ls;
            a[i] = ldfrag(&As[row * 32 + (g ^ ((row >> 1) & 3)) * 8]);
        }
        #pragma unroll
        for (int j = 0; j < 4; j++) {
            int row = wn + j * 16 + ls;
            b[j] = ldfrag(&Bs[row * 32 + (g ^ ((row >> 1) & 3)) * 8]);
        }
        #pragma unroll
        for (int i = 0; i < 4; i++)
            #pragma unroll
            for (int j = 0; j < 4; j++)
                acc[i][j] = __builtin_amdgcn_mfma_f32_16x16x32_bf16(a[i], b[j], acc[i][j], 0, 0, 0);
        __syncthreads();
    }
    #pragma unroll
    for (int i = 0; i < 4; i++)
        #pragma unroll
        for (int j = 0; j < 4; j++) {
            int col = n0 + wn + j * 16 + ls;
            float bv = bias ? bias[col] : 0.f;
            #pragma unroll
            for (int r = 0; r < 4; r++) {
                int row = m0 + wm + i * 16 + g * 4 + r;
                u16 val = f2bf(acc[i][j][r] + bv);
                if (xp_mode) {
                    int b_ = row >> 10, s_ = row & 1023;
                    int gate = col >> 9, u = col & 511;
                    int jj = u >> 5, uu = u & 31;
                    Cb[(((size_t)jj * 1024 + s_) * 16 + b_) * 128 + gate * 32 + uu] = val;
                } else {
                    Cb[(size_t)row * ldc + col] = val;
                }
            }
        }
}

// ---------------- fused attention: per (batch, 32-row q tile)  [QBLK=32, R14-proven]
__global__ __launch_bounds__(256) void k_attn(const u16* __restrict__ qkv, const u16* __restrict__ vt,
                                              u16* __restrict__ attnO) {
    __shared__ u16 P[32 * 1024];     // 64 KB
    __shared__ float mbuf[4][32], lbuf[4][32];
    int b = blockIdx.x >> 5, qt = blockIdx.x & 31;
    int q0 = qt * 32;
    int lane = threadIdx.x & 63, w = threadIdx.x >> 6;
    int ls = lane & 15, g = lane >> 4;
    const float sc = 0.04419417382f;  // 1/sqrt(512)

    f32x4 acc[2][16] = {};
    const u16* Qp0 = qkv + (size_t)(b * 1024 + q0 + ls) * 1536 + g * 8;
    const u16* Qp1 = Qp0 + (size_t)16 * 1536;
    const u16* Kp = qkv + (size_t)(b * 1024 + w * 256 + ls) * 1536 + 512 + g * 8;
    for (int k0 = 0; k0 < 512; k0 += 32) {
        bf16x8 a0 = ldfrag(Qp0 + k0);
        bf16x8 a1 = ldfrag(Qp1 + k0);
        #pragma unroll
        for (int f = 0; f < 16; f++) {
            bf16x8 bb = ldfrag(Kp + (size_t)f * 16 * 1536 + k0);
            acc[0][f] = __builtin_amdgcn_mfma_f32_16x16x32_bf16(a0, bb, acc[0][f], 0, 0, 0);
            acc[1][f] = __builtin_amdgcn_mfma_f32_16x16x32_bf16(a1, bb, acc[1][f], 0, 0, 0);
        }
    }
    float mx[2][4] = {{-1e30f, -1e30f, -1e30f, -1e30f}, {-1e30f, -1e30f, -1e30f, -1e30f}};
    #pragma unroll
    for (int t = 0; t < 2; t++)
        #pragma unroll
        for (int f = 0; f < 16; f++)
            #pragma unroll
            for (int r = 0; r < 4; r++) mx[t][r] = fmaxf(mx[t][r], acc[t][f][r]);
    #pragma unroll
    for (int d = 1; d < 16; d <<= 1)
        #pragma unroll
        for (int t = 0; t < 2; t++)
            #pragma unroll
            for (int r = 0; r < 4; r++) mx[t][r] = fmaxf(mx[t][r], __shfl_xor(mx[t][r], d, 64));
    if (ls == 0)
        #pragma unroll
        for (int t = 0; t < 2; t++)
            #pragma unroll
            for (int r = 0; r < 4; r++) mbuf[w][t * 16 + g * 4 + r] = mx[t][r];
    __syncthreads();
    float m[2][4];
    #pragma unroll
    for (int t = 0; t < 2; t++)
        #pragma unroll
        for (int r = 0; r < 4; r++) {
            int row = t * 16 + g * 4 + r;
            m[t][r] = fmaxf(fmaxf(mbuf[0][row], mbuf[1][row]), fmaxf(mbuf[2][row], mbuf[3][row])) * sc;
        }
    float sum[2][4] = {};
    #pragma unroll
    for (int t = 0; t < 2; t++)
        #pragma unroll
        for (int f = 0; f < 16; f++)
            #pragma unroll
            for (int r = 0; r < 4; r++) {
                int row = t * 16 + g * 4 + r, col = w * 256 + f * 16 + ls;
                float e = __expf(acc[t][f][r] * sc - m[t][r]);
                sum[t][r] += e;
                P[(row * 1024 + col) ^ ((row & 7) << 3)] = f2bf(e);
            }
    #pragma unroll
    for (int d = 1; d < 16; d <<= 1)
        #pragma unroll
        for (int t = 0; t < 2; t++)
            #pragma unroll
            for (int r = 0; r < 4; r++) sum[t][r] += __shfl_xor(sum[t][r], d, 64);
    if (ls == 0)
        #pragma unroll
        for (int t = 0; t < 2; t++)
            #pragma unroll
            for (int r = 0; r < 4; r++) lbuf[w][t * 16 + g * 4 + r] = sum[t][r];
    __syncthreads();

    f32x4 o[2][8] = {};
    const bf16x8* Pv = reinterpret_cast<const bf16x8*>(P);
    const u16* Vp = vt + (size_t)b * 512 * 1024 + (size_t)(w * 128 + ls) * 1024 + g * 8;
    for (int k0 = 0; k0 < 1024; k0 += 32) {
        bf16x8 a0 = Pv[(ls * 128 + (k0 >> 3) + g) ^ (ls & 7)];
        bf16x8 a1 = Pv[((16 + ls) * 128 + (k0 >> 3) + g) ^ (ls & 7)];
        #pragma unroll
        for (int q = 0; q < 8; q++) {
            bf16x8 bb = ldfrag(Vp + (size_t)q * 16 * 1024 + k0);
            o[0][q] = __builtin_amdgcn_mfma_f32_16x16x32_bf16(a0, bb, o[0][q], 0, 0, 0);
            o[1][q] = __builtin_amdgcn_mfma_f32_16x16x32_bf16(a1, bb, o[1][q], 0, 0, 0);
        }
    }
    #pragma unroll
    for (int t = 0; t < 2; t++)
        #pragma unroll
        for (int q = 0; q < 8; q++) {
            int col = w * 128 + q * 16 + ls;
            #pragma unroll
            for (int r = 0; r < 4; r++) {
                int row = t * 16 + g * 4 + r;
                float l = lbuf[0][row] + lbuf[1][row] + lbuf[2][row] + lbuf[3][row];
                attnO[(size_t)(b * 1024 + q0 + row) * 512 + col] = f2bf(o[t][q][r] / l);
            }
        }
}

// ---------------- proj Wo + residual(emb) + LayerNorm -> out1 (f32 + bf16)
__global__ __launch_bounds__(256) void k_projln(const u16* __restrict__ attnO, const u16* __restrict__ WoT,
                                                const float* __restrict__ emb, const float* __restrict__ gamma,
                                                const float* __restrict__ beta, float* __restrict__ out1f,
                                                u16* __restrict__ out1b) {
    __shared__ float buf[16][512];
    int m0 = blockIdx.x * 16;
    int lane = threadIdx.x & 63, w = threadIdx.x >> 6;
    int ls = lane & 15, g = lane >> 4;
    f32x4 acc[8] = {};
    const u16* Ap = attnO + (size_t)(m0 + ls) * 512 + g * 8;
    const u16* Bp = WoT + (size_t)(w * 128 + ls) * 512 + g * 8;
    for (int k0 = 0; k0 < 512; k0 += 32) {
        bf16x8 a = ldfrag(Ap + k0);
        #pragma unroll
        for (int q = 0; q < 8; q++) {
            bf16x8 bb = ldfrag(Bp + (size_t)q * 16 * 512 + k0);
            acc[q] = __builtin_amdgcn_mfma_f32_16x16x32_bf16(a, bb, acc[q], 0, 0, 0);
        }
    }
    #pragma unroll
    for (int q = 0; q < 8; q++) {
        int col = w * 128 + q * 16 + ls;
        #pragma unroll
        for (int r = 0; r < 4; r++) {
            int row = g * 4 + r;
            buf[row][col] = acc[q][r] + emb[(size_t)(m0 + row) * 512 + col];
        }
    }
    __syncthreads();
    int row = threadIdx.x >> 4, c0 = threadIdx.x & 15;
    float s = 0.f, s2 = 0.f;
    for (int c = c0; c < 512; c += 16) { float x = buf[row][c]; s += x; s2 += x * x; }
    #pragma unroll
    for (int d = 1; d < 16; d <<= 1) { s += __shfl_xor(s, d, 64); s2 += __shfl_xor(s2, d, 64); }
    float mu = s * (1.f / 512.f);
    float var = s2 * (1.f / 512.f) - mu * mu;
    float rs = rsqrtf(var + 1e-3f);
    for (int c = c0; c < 512; c += 16) {
        float y = gamma[c] * (buf[row][c] - mu) * rs + beta[c];
        out1f[(size_t)(m0 + row) * 512 + c] = y;
        out1b[(size_t)(m0 + row) * 512 + c] = f2bf(y);
    }
}

// ---------------- persistent LSTM scan: 16 blocks, all 1024 steps in-kernel.
// Tagged-u64 exchange + pre-sample sleep(14) — measured optimum (10<14>16).
__global__ __launch_bounds__(256) void k_lstm(const u16* __restrict__ xpp, const u16* __restrict__ rT,
                                              ull* hbuf /*2 slots x 4096 u64*/, float* __restrict__ hseq) {
    int j = blockIdx.x;
    int tid = threadIdx.x;
    int lane = tid & 63, w = tid >> 6;
    int ls = lane & 15, g = lane >> 4;
    __shared__ float z[16][132];   // padded row stride
    __shared__ u16 hb[8192];       // h[16][512], XOR-swizzled: byte ^= (row&7)<<4
    __shared__ u16 xb[2][2048];
    u32* hb32 = (u32*)hb;

    // R slice -> registers
    bf16x8 rf[2][16];
    {
        const u16* Bp = rT + (size_t)(w * 512 + j * 32 + ls) * 512 + g * 8;
        #pragma unroll
        for (int q = 0; q < 2; q++)
            #pragma unroll
            for (int kk = 0; kk < 16; kk++)
                rf[q][kk] = ldfrag(Bp + (size_t)q * 16 * 512 + kk * 32);
    }
    float cA = 0.f, cB = 0.f;

    for (int i = tid; i < 4096; i += 256) hb32[i] = 0;
    {
        uint4 v = *reinterpret_cast<const uint4*>(xpp + ((size_t)j * 1024) * 2048 + tid * 8);
        *reinterpret_cast<uint4*>(&xb[0][tid * 8]) = v;
    }
    __syncthreads();

    int bb_ = tid >> 4, uu0 = (tid & 15) * 2;
    int eprod = bb_ * 256 + j * 16 + (uu0 >> 1);

    for (int s = 0; s < 1024; s++) {
        uint4 nx;
        if (s + 1 < 1024)
            nx = *reinterpret_cast<const uint4*>(xpp + ((size_t)j * 1024 + s + 1) * 2048 + tid * 8);

        // z = h @ R
        f32x4 acc[2] = {};
        #pragma unroll
        for (int kk = 0; kk < 16; kk++) {
            int aidx = (ls * 512 + kk * 32 + g * 8) ^ ((ls & 7) << 3);
            bf16x8 a = ldfrag(&hb[aidx]);
            acc[0] = __builtin_amdgcn_mfma_f32_16x16x32_bf16(a, rf[0][kk], acc[0], 0, 0, 0);
            acc[1] = __builtin_amdgcn_mfma_f32_16x16x32_bf16(a, rf[1][kk], acc[1], 0, 0, 0);
        }
        #pragma unroll
        for (int q = 0; q < 2; q++)
            #pragma unroll
            for (int r = 0; r < 4; r++)
                z[g * 4 + r][w * 32 + q * 16 + ls] = acc[q][r];
        __syncthreads();   // (A) all hb reads + z writes complete

        // gates
        float hres0, hres1;
        {
            const u16* xr = &xb[s & 1][bb_ * 128];
            #pragma unroll
            for (int p = 0; p < 2; p++) {
                int uu = uu0 + p;
                float zi = z[bb_][uu]      + bf2f(xr[uu]);
                float zf = z[bb_][32 + uu] + bf2f(xr[32 + uu]);
                float zg = z[bb_][64 + uu] + bf2f(xr[64 + uu]);
                float zo = z[bb_][96 + uu] + bf2f(xr[96 + uu]);
                float ii = 1.f / (1.f + __expf(-zi));
                float ff = 1.f / (1.f + __expf(-zf));
                float gg = fmaxf(zg, 0.f);
                float oo = 1.f / (1.f + __expf(-zo));
                float cp = p ? cB : cA;
                float cn = ff * cp + ii * gg;
                if (p) cB = cn; else cA = cn;
                float h = oo * fmaxf(cn, 0.f);
                if (p) hres1 = h; else hres0 = h;
            }
        }

        if (s + 1 < 1024) {
            // publish h(s+1): single tagged u64, fire-and-forget
            ull pk = ((ull)((u32)f2bf(hres0) | ((u32)f2bf(hres1) << 16)) << 32) | (u32)(s + 1);
            __hip_atomic_store(hbuf + ((s + 1) & 1) * 4096 + eprod, pk,
                               __ATOMIC_RELAXED, __HIP_MEMORY_SCOPE_AGENT);
        }
        // hseq out (HBM, overlaps the exchange)
        *reinterpret_cast<float2*>(&hseq[((size_t)bb_ * 1024 + s) * 512 + j * 32 + uu0]) =
            make_float2(hres0, hres1);
        if (s + 1 < 1024)
            *reinterpret_cast<uint4*>(&xb[(s + 1) & 1][tid * 8]) = nx;

        if (s + 1 < 1024) {
            // delay first sample so producer stores are LLC-visible
            __builtin_amdgcn_s_sleep(14);   // measured optimum (R13: 14 > 10; R15: 14 > 16)
            const ull* src = hbuf + ((s + 1) & 1) * 4096;
            u32 want = (u32)(s + 1);
            ull v[16];
            #pragma unroll
            for (int i = 0; i < 16; i++)
                v[i] = __hip_atomic_load(src + i * 256 + tid,
                                         __ATOMIC_RELAXED, __HIP_MEMORY_SCOPE_AGENT);
            u32 stale = 0;
            #pragma unroll
            for (int i = 0; i < 16; i++)
                stale |= (u32)((u32)v[i] != want) << i;
            while (stale) {
                __builtin_amdgcn_s_sleep(1);
                #pragma unroll
                for (int i = 0; i < 16; i++)
                    if (stale & (1u << i))
                        v[i] = __hip_atomic_load(src + i * 256 + tid,
                                                 __ATOMIC_RELAXED, __HIP_MEMORY_SCOPE_AGENT);
                u32 ns = 0;
                #pragma unroll
                for (int i = 0; i < 16; i++)
                    ns |= (u32)((u32)v[i] != want) << i;
                stale = ns;
            }
            // refill hb (own targets only; barrier (A) fenced all prior reads)
            #pragma unroll
            for (int i = 0; i < 16; i++) {
                int e = i * 256 + tid;
                int b = e >> 8, up = e & 255;
                hb32[(b * 256 + up) ^ ((b & 7) << 2)] = (u32)(v[i] >> 32);
            }
            __syncthreads();   // (C) refill visible before next MFMA
        }
    }
}

// ---------------- final LN in place on d_out: out = LN(d_out + out1f)
__global__ __launch_bounds__(256) void k_finln(float* __restrict__ io, const float* __restrict__ res,
                                               const float* __restrict__ gamma, const float* __restrict__ beta) {
    int m0 = blockIdx.x * 16;
    int row = threadIdx.x >> 4, c0 = threadIdx.x & 15;
    size_t base = (size_t)(m0 + row) * 512;
    float x[32];
    float s = 0.f, s2 = 0.f;
    #pragma unroll
    for (int i = 0; i < 32; i++) {
        int cc = c0 + i * 16;
        x[i] = io[base + cc] + res[base + cc];
        s += x[i]; s2 += x[i] * x[i];
    }
    #pragma unroll
    for (int d = 1; d < 16; d <<= 1) { s += __shfl_xor(s, d, 64); s2 += __shfl_xor(s2, d, 64); }
    float mu = s * (1.f / 512.f);
    float var = s2 * (1.f / 512.f) - mu * mu;
    float rs = rsqrtf(var + 1e-3f);
    #pragma unroll
    for (int i = 0; i < 32; i++) {
        int cc = c0 + i * 16;
        io[base + cc] = gamma[cc] * (x[i] - mu) * rs + beta[cc];
    }
}

extern "C" void kernel_launch(void* const* d_in, const int* in_sizes, int n_in,
                              void* d_out, int out_size, void* d_ws, size_t ws_size,
                              hipStream_t stream) {
    (void)in_sizes; (void)n_in; (void)out_size; (void)ws_size;
    const float* emb   = (const float*)d_in[0];
    const float* Wq    = (const float*)d_in[1];
    const float* Wk    = (const float*)d_in[2];
    const float* Wv    = (const float*)d_in[3];
    const float* Wo    = (const float*)d_in[4];
    const float* gamma = (const float*)d_in[5];
    const float* beta  = (const float*)d_in[6];
    const float* lk    = (const float*)d_in[7];
    const float* lr    = (const float*)d_in[8];
    const float* lb    = (const float*)d_in[9];

    char* w = (char*)d_ws;
    size_t o = 0;
    u16* WqkvT = (u16*)(w + o); o += (size_t)1536 * 512 * 2;
    u16* WoT   = (u16*)(w + o); o += (size_t)512 * 512 * 2;
    u16* kT    = (u16*)(w + o); o += (size_t)2048 * 512 * 2;
    u16* rT    = (u16*)(w + o); o += (size_t)2048 * 512 * 2;
    u16* Xbf   = (u16*)(w + o); o += (size_t)16384 * 512 * 2;     // reused as attnO
    u16* QKV   = (u16*)(w + o); o += (size_t)16384 * 1536 * 2;    // reused (with Vt) as xpp
    u16* Vt    = (u16*)(w + o); o += (size_t)16 * 512 * 1024 * 2;
    float* out1f = (float*)(w + o); o += (size_t)16384 * 512 * 4;
    u16* out1b = (u16*)(w + o); o += (size_t)16384 * 512 * 2;
    ull* hbuf  = (ull*)(w + o);  o += (size_t)2 * 4096 * 8;
    u16* attnO = Xbf;   // Xbf dead after QKV GEMM
    u16* xpp   = QKV;   // QKV+Vt dead after attention
    float* outp = (float*)d_out;

    k_cvt<<<8192, 256, 0, stream>>>(emb, Xbf, 16384 * 512, hbuf);
    k_tr4<<<dim3(16, 16, 4), 256, 0, stream>>>(Wq, Wk, Wv, Wo, WqkvT, WoT);
    k_tr2<<<dim3(64, 16, 2), 256, 0, stream>>>(lk, lr, kT, rT);
    k_gemm<<<128 * 12, 256, 0, stream>>>(Xbf, WqkvT, QKV, nullptr, 16384, 1536, 512, 1536, 0);
    k_tr_v<<<dim3(32, 16, 16), 256, 0, stream>>>(QKV, Vt);
    k_attn<<<512, 256, 0, stream>>>(QKV, Vt, attnO);
    k_projln<<<1024, 256, 0, stream>>>(attnO, WoT, emb, gamma, beta, out1f, out1b);
    k_gemm<<<128 * 16, 256, 0, stream>>>(out1b, kT, xpp, lb, 16384, 2048, 512, 2048, 1);
    k_lstm<<<16, 256, 0, stream>>>(xpp, rT, hbuf, outp);
    k_finln<<<1024, 256, 0, stream>>>(outp, out1f, gamma, beta);
}